// Round 10
// baseline (373.726 us; speedup 1.0000x reference)
//
#include <hip/hip_runtime.h>
#include <hip/hip_bf16.h>
#include <hip/hip_fp16.h>

// ScannedRNN (GRU with resets), T=512 B=256 H=INP=256, MI355X gfx950.
//
// Round 10: r9 (M=32, 32 chunks x 16 steps) with s8-OUTER MFMA loop:
//   per s8: {wz1, wn1, af(m=0), af(m=1)} = 4 LDS b128 reads + 12 MFMA.
//   -> 32 LDS reads/wave/step (was 48); w2 shared across both m-phases;
//   12 named accumulators, gi C-in init (gr/gz dead during MFMA).
// Unchanged: weights {r0,r1,z0,n0} in 128 AGPRs + {z1,n1} in 128 KiB LDS;
//   A-tile 32x256 bf16 dbuf (32 KiB) -> 160 KiB LDS total; sigma K-pairing
//   with v_cvt_pk_bf16_f32 h-writes; exp2-folded activations; single
//   lgkm-only barrier/step; single-buffered gi (L3-resident); exact reset
//   lookback; h fp32 in regs; nontemporal out stores.

#define T_LEN 512
#define BATCH 256
#define HID   256
#define CHL   16                    /* steps per chunk */

#define LOG2E     1.4426950408889634f
#define TWO_LOG2E 2.8853900817779268f

typedef __attribute__((ext_vector_type(8))) short s16x8;          // 8 bf16
typedef __attribute__((ext_vector_type(8))) unsigned short u16x8; // 8 f16
typedef __attribute__((ext_vector_type(4))) float fx4;            // 4 f32 acc

#define MFMA16 __builtin_amdgcn_mfma_f32_16x16x32_bf16
#define BLKH  24576u                /* halves per (t,bt32) gi block (48 KiB) */
#define TSTRH 196608u               /* 8 blocks per t */

__device__ __forceinline__ unsigned short f2bf(float f) {
  union { float f; unsigned u; } v; v.f = f;
  unsigned r = v.u + 0x7fffu + ((v.u >> 16) & 1u);   // RNE
  return (unsigned short)(r >> 16);
}

__device__ __forceinline__ unsigned cvt_pk_bf16(float lo, float hi) {
  unsigned r;
  asm("v_cvt_pk_bf16_f32 %0, %1, %2" : "=v"(r) : "v"(lo), "v"(hi));
  return r;
}

__device__ __forceinline__ s16x8 pack8(float4 a, float4 b, float s) {  // natural K
  s16x8 f;
  f[0] = (short)f2bf(a.x * s); f[1] = (short)f2bf(a.y * s);
  f[2] = (short)f2bf(a.z * s); f[3] = (short)f2bf(a.w * s);
  f[4] = (short)f2bf(b.x * s); f[5] = (short)f2bf(b.y * s);
  f[6] = (short)f2bf(b.z * s); f[7] = (short)f2bf(b.w * s);
  return f;
}

__device__ __forceinline__ s16x8 pack8i(float4 a, float4 b, float s) { // sigma K
  s16x8 f;
  f[0] = (short)f2bf(a.x * s); f[1] = (short)f2bf(b.x * s);
  f[2] = (short)f2bf(a.y * s); f[3] = (short)f2bf(b.y * s);
  f[4] = (short)f2bf(a.z * s); f[5] = (short)f2bf(b.z * s);
  f[6] = (short)f2bf(a.w * s); f[7] = (short)f2bf(b.w * s);
  return f;
}

// wrA[0]=r/ht0  wrA[1]=r/ht1  wrA[2]=z/ht0  wrA[3]=n/ht0   (128 regs -> AGPR)
// Wlds 128 KiB: set0 = z/ht1 (64K), set1 = n/ht1 (64K); line [set][wv][s8][lane].
// All weights pre-scaled: r,z rows * LOG2E ; n rows * 2*LOG2E.
template<bool SIGMA>
__device__ __forceinline__ void load_weights(const float* __restrict__ W,
                                             s16x8 (&wrA)[4][8], char* Wlds,
                                             int tid, int wid, int col, int kgrp) {
  const int rowbase[4] = {0, 16, 256, 512};
  const float scl[4] = {LOG2E, LOG2E, LOG2E, TWO_LOG2E};
#pragma unroll
  for (int k = 0; k < 4; ++k) {
    int row = rowbase[k] + wid * 32 + col;
#pragma unroll
    for (int s8 = 0; s8 < 8; ++s8) {
      if (SIGMA) {
        const float* pa = W + row * 256 + s8 * 32 + kgrp * 4;
        wrA[k][s8] = pack8i(*(const float4*)pa, *(const float4*)(pa + 16), scl[k]);
      } else {
        const float* pa = W + row * 256 + s8 * 32 + kgrp * 8;
        wrA[k][s8] = pack8(*(const float4*)pa, *(const float4*)(pa + 4), scl[k]);
      }
    }
  }
#pragma unroll
  for (int q = 0; q < 16; ++q) {
    int li = tid + q * 512;             // 8192 lines of 16 B
    int set = li >> 12, wv = (li >> 9) & 7, s8 = (li >> 6) & 7, l = li & 63;
    int row = (set ? 512 : 256) + wv * 32 + 16 + (l & 15);
    float s = set ? TWO_LOG2E : LOG2E;
    s16x8 line;
    if (SIGMA) {
      const float* pa = W + row * 256 + s8 * 32 + (l >> 4) * 4;
      line = pack8i(*(const float4*)pa, *(const float4*)(pa + 16), s);
    } else {
      const float* pa = W + row * 256 + s8 * 32 + (l >> 4) * 8;
      line = pack8(*(const float4*)pa, *(const float4*)(pa + 4), s);
    }
    *(s16x8*)(Wlds + li * 16) = line;
  }
}

__device__ __forceinline__ void soft_barrier() {
  asm volatile("s_waitcnt lgkmcnt(0)" ::: "memory");
  __builtin_amdgcn_s_barrier();
  __builtin_amdgcn_sched_barrier(0);
  asm volatile("" ::: "memory");
}

// ---------------- Kernel A: input projection -> gi (f16, pre-scaled) ------
__global__ __launch_bounds__(512, 2) void gi_proj_kernel(
    const float* __restrict__ X, const float* __restrict__ w_ih,
    const float* __restrict__ b_ih, const float* __restrict__ b_hh,
    __half* __restrict__ gi) {
  __shared__ __align__(16) char Wlds[131072];
  __shared__ __align__(16) char Ald[2][16384];   // 32x256 bf16, swizzled, dbuf

  const int tid = threadIdx.x;
  const int wid = tid >> 6, lane = tid & 63;
  const int col = lane & 15, kgrp = lane >> 4;

  s16x8 wrA[4][8];
  load_weights<false>(w_ih, wrA, Wlds, tid, wid, col, kgrp);

  float bias[2][3];
#pragma unroll
  for (int ht = 0; ht < 2; ++ht) {
    int gb = wid * 32 + ht * 16 + col;
    bias[ht][0] = (b_ih[gb]       + b_hh[gb])       * LOG2E;   // r (b_hh folded)
    bias[ht][1] = (b_ih[256 + gb] + b_hh[256 + gb]) * LOG2E;   // z (b_hh folded)
    bias[ht][2] = b_ih[512 + gb] * TWO_LOG2E;                  // n (b_hh in scan)
  }

  const int srow = tid >> 4, skb = tid & 15;   // 32 rows x 16 col-blocks
  const unsigned sx = (unsigned)(srow & 7) << 4;
  const unsigned sb0 = (unsigned)(srow * 512 + skb * 32);

  float4 xc0, xc1, xc2, xc3;
  {
    const float* xp = X + (size_t)(blockIdx.x * 32 + srow) * 256 + skb * 16;
    xc0 = *(const float4*)(xp); xc1 = *(const float4*)(xp + 4);
    xc2 = *(const float4*)(xp + 8); xc3 = *(const float4*)(xp + 12);
  }

  int parity = 0;
  for (int c32 = blockIdx.x; c32 < 4096; c32 += 256) {
    char* ab = Ald[parity];
    {
      uint4 u0, u1;
      u0.x = cvt_pk_bf16(xc0.x, xc0.y); u0.y = cvt_pk_bf16(xc0.z, xc0.w);
      u0.z = cvt_pk_bf16(xc1.x, xc1.y); u0.w = cvt_pk_bf16(xc1.z, xc1.w);
      u1.x = cvt_pk_bf16(xc2.x, xc2.y); u1.y = cvt_pk_bf16(xc2.z, xc2.w);
      u1.z = cvt_pk_bf16(xc3.x, xc3.y); u1.w = cvt_pk_bf16(xc3.z, xc3.w);
      *(uint4*)(ab + (sb0 ^ sx)) = u0;
      *(uint4*)(ab + ((sb0 + 16) ^ sx)) = u1;
    }
    int nc = c32 + 256;
    if (nc < 4096) {
      const float* xp = X + (size_t)(nc * 32 + srow) * 256 + skb * 16;
      xc0 = *(const float4*)(xp); xc1 = *(const float4*)(xp + 4);
      xc2 = *(const float4*)(xp + 8); xc3 = *(const float4*)(xp + 12);
    }
    soft_barrier();   // stage visible; X prefetch + gi stores stay in flight

    __half* gb = gi + (size_t)c32 * BLKH + (unsigned)(wid * 64 + lane) * 48;
#pragma unroll
    for (int m = 0; m < 2; ++m) {
      fx4 aR0, aR1, aZ0, aZ1, aN0, aN1;
#pragma unroll
      for (int j = 0; j < 4; ++j) {
        aR0[j] = bias[0][0]; aR1[j] = bias[1][0];
        aZ0[j] = bias[0][1]; aZ1[j] = bias[1][1];
        aN0[j] = bias[0][2]; aN1[j] = bias[1][2];
      }
#pragma unroll
      for (int s8 = 0; s8 < 8; ++s8) {
        unsigned aoff = ((unsigned)((m * 16 + col) * 512 + s8 * 64 + kgrp * 16)) ^
                        ((unsigned)(col & 7) << 4);
        s16x8 af  = *(const s16x8*)(ab + aoff);
        s16x8 wz1 = *(const s16x8*)(Wlds + (wid * 512 + s8 * 64 + lane) * 16);
        s16x8 wn1 = *(const s16x8*)(Wlds + 65536 + (wid * 512 + s8 * 64 + lane) * 16);
        aR0 = MFMA16(af, wrA[0][s8], aR0, 0, 0, 0);
        aR1 = MFMA16(af, wrA[1][s8], aR1, 0, 0, 0);
        aZ0 = MFMA16(af, wrA[2][s8], aZ0, 0, 0, 0);
        aZ1 = MFMA16(af, wz1, aZ1, 0, 0, 0);
        aN0 = MFMA16(af, wrA[3][s8], aN0, 0, 0, 0);
        aN1 = MFMA16(af, wn1, aN1, 0, 0, 0);
      }
      u16x8 oR, oZ, oN;
#pragma unroll
      for (int j = 0; j < 4; ++j) {
        oR[j] = __half_as_ushort(__float2half(aR0[j]));
        oR[4 + j] = __half_as_ushort(__float2half(aR1[j]));
        oZ[j] = __half_as_ushort(__float2half(aZ0[j]));
        oZ[4 + j] = __half_as_ushort(__float2half(aZ1[j]));
        oN[j] = __half_as_ushort(__float2half(aN0[j]));
        oN[4 + j] = __half_as_ushort(__float2half(aN1[j]));
      }
      *(u16x8*)(gb + m * 8) = oR;
      *(u16x8*)(gb + 16 + m * 8) = oZ;
      *(u16x8*)(gb + 32 + m * 8) = oN;
    }
    parity ^= 1;
  }
}

// ---------------- Kernel B: chunked GRU scan (M=32, s8-outer) ----------------
__global__ __launch_bounds__(512, 2) void gru_scan_kernel(
    const float* __restrict__ carry, const __half* __restrict__ gi,
    const int* __restrict__ resets, const float* __restrict__ w_hh,
    const float* __restrict__ b_hh, float* __restrict__ out) {
  __shared__ __align__(16) char Wlds[131072];
  __shared__ __align__(16) char Ald[2][16384];   // h bf16 A-tile (sigma), dbuf
  int* lastreset = (int*)(Ald[1]);               // aliased (prologue only)

  const int tid = threadIdx.x;
  const int wid = tid >> 6, lane = tid & 63;
  const int col = lane & 15, kgrp = lane >> 4;
  const int bid = blockIdx.x;
  const int bt = bid & 7, c = bid >> 3;
  const int b0 = bt * 32, t0 = c * CHL, t1 = t0 + CHL;
  const int hid0 = wid * 32 + col;

  s16x8 wrA[4][8];
  load_weights<true>(w_hh, wrA, Wlds, tid, wid, col, kgrp);
  const float bhhn0 = b_hh[512 + hid0] * TWO_LOG2E;
  const float bhhn1 = b_hh[512 + hid0 + 16] * TWO_LOG2E;

  // ---- exact scan start: min over 32-b tile of (last reset < t0) ----
  int s, useCarry;
  if (c == 0) {
    s = 0; useCarry = 1;
  } else {
    if (tid < 32) lastreset[tid] = -1;
    for (int base = t0 - 16;; base -= 16) {   // 512 thr: 16 t x 32 b per pass
      __syncthreads();
      int tt = base + (tid >> 5);
      if (tt >= 0 && tt < t0) {
        if (resets[tt * BATCH + b0 + (tid & 31)] != 0)
          atomicMax(&lastreset[tid & 31], tt);
      }
      __syncthreads();
      int mn = t0, all = 1;
#pragma unroll
      for (int i = 0; i < 32; ++i) {
        int v = lastreset[i];
        all &= (v >= 0) ? 1 : 0;
        mn = min(mn, v < 0 ? t0 : v);
      }
      if (all) { s = mn; useCarry = 0; break; }
      if (base <= 0) { s = 0; useCarry = 1; break; }
    }
    __syncthreads();   // lastreset reads done before Ald[1] is reused
  }

  // ---- init state at t=s into Ald[0] (sigma pairs (hid,hid+16)) ----
  {
    int row = tid >> 4, kblk = tid & 15;
    int rst = resets[s * BATCH + b0 + row];
    float4 va0 = {0.f, 0.f, 0.f, 0.f}, va1 = va0, vb0 = va0, vb1 = va0;
    if (useCarry && !rst) {
      const float* cp = carry + (size_t)(b0 + row) * HID + (kblk >> 1) * 32 + (kblk & 1) * 8;
      va0 = *(const float4*)(cp);      va1 = *(const float4*)(cp + 4);
      vb0 = *(const float4*)(cp + 16); vb1 = *(const float4*)(cp + 20);
    }
    uint4 u0, u1;
    u0.x = cvt_pk_bf16(va0.x, vb0.x); u0.y = cvt_pk_bf16(va0.y, vb0.y);
    u0.z = cvt_pk_bf16(va0.z, vb0.z); u0.w = cvt_pk_bf16(va0.w, vb0.w);
    u1.x = cvt_pk_bf16(va1.x, vb1.x); u1.y = cvt_pk_bf16(va1.y, vb1.y);
    u1.z = cvt_pk_bf16(va1.z, vb1.z); u1.w = cvt_pk_bf16(va1.w, vb1.w);
    unsigned sx = (unsigned)(row & 7) << 4;
    unsigned sb0 = (unsigned)(row * 512 + kblk * 32);
    *(uint4*)(Ald[0] + (sb0 ^ sx)) = u0;
    *(uint4*)(Ald[0] + ((sb0 + 16) ^ sx)) = u1;
  }
  float hprev[2][2][4];
#pragma unroll
  for (int m = 0; m < 2; ++m)
#pragma unroll
    for (int j = 0; j < 4; ++j) {
      int b = b0 + m * 16 + kgrp * 4 + j;
      int rst = resets[s * BATCH + b];
      float h0 = 0.f, h1 = 0.f;
      if (useCarry && !rst) {
        h0 = carry[(size_t)b * HID + hid0];
        h1 = carry[(size_t)b * HID + hid0 + 16];
      }
      hprev[m][0][j] = h0; hprev[m][1][j] = h1;
    }

  const __half* gb = gi + (size_t)(s * 8 + bt) * BLKH + (unsigned)(wid * 64 + lane) * 48;
  float* opc = out + 65536 + ((size_t)s * BATCH + b0 + kgrp * 4) * HID + hid0;
  __syncthreads();

  // ---- pipelined scan: single-buffered gi, s8-outer MFMA ----
  for (int t = s; t < t1; ++t) {
    // VMEM loads (L3-resident gi) issued at step top
    u16x8 gr0 = *(const u16x8*)(gb);
    u16x8 gr1 = *(const u16x8*)(gb + 8);
    u16x8 gz0 = *(const u16x8*)(gb + 16);
    u16x8 gz1 = *(const u16x8*)(gb + 24);
    u16x8 gn0 = *(const u16x8*)(gb + 32);
    u16x8 gn1 = *(const u16x8*)(gb + 40);
    int tn = (t + 1 < T_LEN) ? t + 1 : T_LEN - 1;
    int4 rn0 = *(const int4*)(resets + (size_t)tn * BATCH + b0 + kgrp * 4);
    int4 rn1 = *(const int4*)(resets + (size_t)tn * BATCH + b0 + 16 + kgrp * 4);

    // C-in init (gr/gz consumed here -> dead during MFMA)
    fx4 aR00, aR01, aZ00, aZ01, aN00, aN01;   // m=0: ht0/ht1
    fx4 aR10, aR11, aZ10, aZ11, aN10, aN11;   // m=1
#pragma unroll
    for (int j = 0; j < 4; ++j) {
      aR00[j] = __half2float(__ushort_as_half(gr0[j]));
      aR01[j] = __half2float(__ushort_as_half(gr0[4 + j]));
      aR10[j] = __half2float(__ushort_as_half(gr1[j]));
      aR11[j] = __half2float(__ushort_as_half(gr1[4 + j]));
      aZ00[j] = __half2float(__ushort_as_half(gz0[j]));
      aZ01[j] = __half2float(__ushort_as_half(gz0[4 + j]));
      aZ10[j] = __half2float(__ushort_as_half(gz1[j]));
      aZ11[j] = __half2float(__ushort_as_half(gz1[4 + j]));
      aN00[j] = bhhn0; aN01[j] = bhhn1;
      aN10[j] = bhhn0; aN11[j] = bhhn1;
    }

    const char* ab = Ald[(t - s) & 1];
#pragma unroll
    for (int s8 = 0; s8 < 8; ++s8) {
      s16x8 wz1 = *(const s16x8*)(Wlds + (wid * 512 + s8 * 64 + lane) * 16);
      s16x8 wn1 = *(const s16x8*)(Wlds + 65536 + (wid * 512 + s8 * 64 + lane) * 16);
      unsigned aoff = ((unsigned)(col * 512 + s8 * 64 + kgrp * 16)) ^
                      ((unsigned)(col & 7) << 4);
      s16x8 af0 = *(const s16x8*)(ab + aoff);
      s16x8 af1 = *(const s16x8*)(ab + aoff + 8192);   // m=1 rows (+16*512B)
      aR00 = MFMA16(af0, wrA[0][s8], aR00, 0, 0, 0);
      aR01 = MFMA16(af0, wrA[1][s8], aR01, 0, 0, 0);
      aZ00 = MFMA16(af0, wrA[2][s8], aZ00, 0, 0, 0);
      aZ01 = MFMA16(af0, wz1, aZ01, 0, 0, 0);
      aN00 = MFMA16(af0, wrA[3][s8], aN00, 0, 0, 0);
      aN01 = MFMA16(af0, wn1, aN01, 0, 0, 0);
      aR10 = MFMA16(af1, wrA[0][s8], aR10, 0, 0, 0);
      aR11 = MFMA16(af1, wrA[1][s8], aR11, 0, 0, 0);
      aZ10 = MFMA16(af1, wrA[2][s8], aZ10, 0, 0, 0);
      aZ11 = MFMA16(af1, wz1, aZ11, 0, 0, 0);
      aN10 = MFMA16(af1, wrA[3][s8], aN10, 0, 0, 0);
      aN11 = MFMA16(af1, wn1, aN11, 0, 0, 0);
    }

    char* aw = (char*)Ald[((t - s) & 1) ^ 1];
    const bool lastT = (t + 1 >= T_LEN);

    // ---- gates m=0 ----
#pragma unroll
    for (int j = 0; j < 4; ++j) {
      int b = kgrp * 4 + j;
      int rj = (j == 0) ? rn0.x : (j == 1) ? rn0.y : (j == 2) ? rn0.z : rn0.w;
      if (lastT) rj = 0;
      float r0 = __builtin_amdgcn_rcpf(1.f + __builtin_amdgcn_exp2f(-aR00[j]));
      float z0 = __builtin_amdgcn_rcpf(1.f + __builtin_amdgcn_exp2f(-aZ00[j]));
      float pn0 = __half2float(__ushort_as_half(gn0[j])) + r0 * aN00[j];
      float n0 = 1.f - 2.f * __builtin_amdgcn_rcpf(1.f + __builtin_amdgcn_exp2f(pn0));
      float h0 = n0 + z0 * (hprev[0][0][j] - n0);
      float r1 = __builtin_amdgcn_rcpf(1.f + __builtin_amdgcn_exp2f(-aR01[j]));
      float z1 = __builtin_amdgcn_rcpf(1.f + __builtin_amdgcn_exp2f(-aZ01[j]));
      float pn1 = __half2float(__ushort_as_half(gn0[4 + j])) + r1 * aN01[j];
      float n1 = 1.f - 2.f * __builtin_amdgcn_rcpf(1.f + __builtin_amdgcn_exp2f(pn1));
      float h1 = n1 + z1 * (hprev[0][1][j] - n1);
      __builtin_nontemporal_store(h0, opc + j * HID);
      __builtin_nontemporal_store(h1, opc + j * HID + 16);
      float hk0 = rj ? 0.f : h0;
      float hk1 = rj ? 0.f : h1;
      hprev[0][0][j] = hk0; hprev[0][1][j] = hk1;
      unsigned hw = cvt_pk_bf16(hk0, hk1);
      unsigned hoff = ((unsigned)(b * 512 + wid * 64 + col * 4)) ^
                      ((unsigned)(b & 7) << 4);
      *(unsigned*)(aw + hoff) = hw;
    }
    // ---- gates m=1 ----
#pragma unroll
    for (int j = 0; j < 4; ++j) {
      int b = 16 + kgrp * 4 + j;
      int rj = (j == 0) ? rn1.x : (j == 1) ? rn1.y : (j == 2) ? rn1.z : rn1.w;
      if (lastT) rj = 0;
      float r0 = __builtin_amdgcn_rcpf(1.f + __builtin_amdgcn_exp2f(-aR10[j]));
      float z0 = __builtin_amdgcn_rcpf(1.f + __builtin_amdgcn_exp2f(-aZ10[j]));
      float pn0 = __half2float(__ushort_as_half(gn1[j])) + r0 * aN10[j];
      float n0 = 1.f - 2.f * __builtin_amdgcn_rcpf(1.f + __builtin_amdgcn_exp2f(pn0));
      float h0 = n0 + z0 * (hprev[1][0][j] - n0);
      float r1 = __builtin_amdgcn_rcpf(1.f + __builtin_amdgcn_exp2f(-aR11[j]));
      float z1 = __builtin_amdgcn_rcpf(1.f + __builtin_amdgcn_exp2f(-aZ11[j]));
      float pn1 = __half2float(__ushort_as_half(gn1[4 + j])) + r1 * aN11[j];
      float n1 = 1.f - 2.f * __builtin_amdgcn_rcpf(1.f + __builtin_amdgcn_exp2f(pn1));
      float h1 = n1 + z1 * (hprev[1][1][j] - n1);
      __builtin_nontemporal_store(h0, opc + 4096 + j * HID);
      __builtin_nontemporal_store(h1, opc + 4096 + j * HID + 16);
      float hk0 = rj ? 0.f : h0;
      float hk1 = rj ? 0.f : h1;
      hprev[1][0][j] = hk0; hprev[1][1][j] = hk1;
      unsigned hw = cvt_pk_bf16(hk0, hk1);
      unsigned hoff = ((unsigned)(b * 512 + wid * 64 + col * 4)) ^
                      ((unsigned)(b & 7) << 4);
      *(unsigned*)(aw + hoff) = hw;
    }

    gb += TSTRH;
    opc += 65536;
    soft_barrier();   // lgkm drain only; gi loads + out stores stay in flight
  }

  if (c == 31) {       // h_final = h after t=511 (reset guarded off)
#pragma unroll
    for (int m = 0; m < 2; ++m)
#pragma unroll
      for (int j = 0; j < 4; ++j) {
        int b = b0 + m * 16 + kgrp * 4 + j;
        out[(size_t)b * HID + hid0] = hprev[m][0][j];
        out[(size_t)b * HID + hid0 + 16] = hprev[m][1][j];
      }
  }
}

extern "C" void kernel_launch(void* const* d_in, const int* in_sizes, int n_in,
                              void* d_out, int out_size, void* d_ws, size_t ws_size,
                              hipStream_t stream) {
  const float* carry = (const float*)d_in[0];
  const float* X     = (const float*)d_in[1];
  const int*   rsts  = (const int*)d_in[2];
  const float* w_ih  = (const float*)d_in[3];
  const float* w_hh  = (const float*)d_in[4];
  const float* b_ih  = (const float*)d_in[5];
  const float* b_hh  = (const float*)d_in[6];
  float* out = (float*)d_out;

  const size_t gi_bytes = (size_t)T_LEN * BATCH * 3 * HID * sizeof(__half);  // 192 MiB
  if (ws_size < gi_bytes) return;
  __half* gi = (__half*)d_ws;

  gi_proj_kernel<<<256, 512, 0, stream>>>(X, w_ih, b_ih, b_hh, gi);
  gru_scan_kernel<<<256, 512, 0, stream>>>(carry, gi, rsts, w_hh, b_hh, out);
}

// Round 11
// 266.321 us; speedup vs baseline: 1.4033x; 1.4033x over previous
//
#include <hip/hip_runtime.h>
#include <hip/hip_bf16.h>
#include <hip/hip_fp16.h>

// ScannedRNN (GRU with resets), T=512 B=256 H=INP=256, MI355X gfx950.
//
// Round 11 (consolidation): r10's M=32 proj (clean, ~75us) + r7's proven
// M=16 scan (151us, zero spill) reading the M=32 gi layout + exp2-folded
// activations (verified r9/r10).
//  - proj: 32-row chunks, weights {r0,r1,z0,n0} in AGPR + {z1,n1} in LDS,
//    writes gi blocks [t][bt32][wid][lane][g][m][ht*4+j] (f16, pre-scaled
//    by log2e / 2log2e).
//  - scan: 16 chunks x 32 steps x 16-batch tiles (256 WGs); weights
//    {r0,r1,z0,z1} in 128 AGPRs + n-gate (both tiles) in 128 KiB LDS;
//    sigma K-pairing (h written as (hid,hid+16) pairs via cvt_pk_bf16);
//    C-in acc init; 1-step gi prefetch (double-buffered registers);
//    one lgkm-only barrier per step; nontemporal out stores.

#define T_LEN 512
#define BATCH 256
#define HID   256

#define LOG2E     1.4426950408889634f
#define TWO_LOG2E 2.8853900817779268f

typedef __attribute__((ext_vector_type(8))) short s16x8;          // 8 bf16
typedef __attribute__((ext_vector_type(8))) unsigned short u16x8; // 8 f16
typedef __attribute__((ext_vector_type(4))) float fx4;            // 4 f32 acc

#define MFMA16 __builtin_amdgcn_mfma_f32_16x16x32_bf16
#define BLKH  24576u                /* halves per (t,bt32) gi block (48 KiB) */
#define TSTRH 196608u               /* 8 blocks per t */

__device__ __forceinline__ unsigned short f2bf(float f) {
  union { float f; unsigned u; } v; v.f = f;
  unsigned r = v.u + 0x7fffu + ((v.u >> 16) & 1u);   // RNE
  return (unsigned short)(r >> 16);
}

__device__ __forceinline__ unsigned cvt_pk_bf16(float lo, float hi) {
  unsigned r;
  asm("v_cvt_pk_bf16_f32 %0, %1, %2" : "=v"(r) : "v"(lo), "v"(hi));
  return r;
}

__device__ __forceinline__ s16x8 pack8(float4 a, float4 b, float s) {  // natural K
  s16x8 f;
  f[0] = (short)f2bf(a.x * s); f[1] = (short)f2bf(a.y * s);
  f[2] = (short)f2bf(a.z * s); f[3] = (short)f2bf(a.w * s);
  f[4] = (short)f2bf(b.x * s); f[5] = (short)f2bf(b.y * s);
  f[6] = (short)f2bf(b.z * s); f[7] = (short)f2bf(b.w * s);
  return f;
}

__device__ __forceinline__ s16x8 pack8i(float4 a, float4 b, float s) { // sigma K
  s16x8 f;
  f[0] = (short)f2bf(a.x * s); f[1] = (short)f2bf(b.x * s);
  f[2] = (short)f2bf(a.y * s); f[3] = (short)f2bf(b.y * s);
  f[4] = (short)f2bf(a.z * s); f[5] = (short)f2bf(b.z * s);
  f[6] = (short)f2bf(a.w * s); f[7] = (short)f2bf(b.w * s);
  return f;
}

__device__ __forceinline__ void soft_barrier() {
  asm volatile("s_waitcnt lgkmcnt(0)" ::: "memory");
  __builtin_amdgcn_s_barrier();
  __builtin_amdgcn_sched_barrier(0);
  asm volatile("" ::: "memory");
}

// ---- proj weights: wrA {r/ht0,r/ht1,z/ht0,n/ht0} AGPR; LDS {z/ht1,n/ht1} ----
__device__ __forceinline__ void load_weights_proj(const float* __restrict__ W,
                                                  s16x8 (&wrA)[4][8], char* Wlds,
                                                  int tid, int wid, int col, int kgrp) {
  const int rowbase[4] = {0, 16, 256, 512};
  const float scl[4] = {LOG2E, LOG2E, LOG2E, TWO_LOG2E};
#pragma unroll
  for (int k = 0; k < 4; ++k) {
    int row = rowbase[k] + wid * 32 + col;
#pragma unroll
    for (int s8 = 0; s8 < 8; ++s8) {
      const float* pa = W + row * 256 + s8 * 32 + kgrp * 8;
      wrA[k][s8] = pack8(*(const float4*)pa, *(const float4*)(pa + 4), scl[k]);
    }
  }
#pragma unroll
  for (int q = 0; q < 16; ++q) {
    int li = tid + q * 512;             // 8192 lines of 16 B
    int set = li >> 12, wv = (li >> 9) & 7, s8 = (li >> 6) & 7, l = li & 63;
    int row = (set ? 512 : 256) + wv * 32 + 16 + (l & 15);
    float s = set ? TWO_LOG2E : LOG2E;
    const float* pa = W + row * 256 + s8 * 32 + (l >> 4) * 8;
    *(s16x8*)(Wlds + li * 16) = pack8(*(const float4*)pa, *(const float4*)(pa + 4), s);
  }
}

// ---- scan weights (r7): wr {r/ht0,r/ht1,z/ht0,z/ht1} AGPR; LDS n both tiles ----
__device__ __forceinline__ void load_weights_scan(const float* __restrict__ W,
                                                  s16x8 (&wr)[4][8], char* Wlds,
                                                  int tid, int wid, int col, int kgrp) {
#pragma unroll
  for (int g = 0; g < 2; ++g)
#pragma unroll
    for (int ht = 0; ht < 2; ++ht) {
      int row = g * 256 + (wid * 2 + ht) * 16 + col;
#pragma unroll
      for (int s8 = 0; s8 < 8; ++s8) {
        const float* pa = W + row * 256 + s8 * 32 + kgrp * 4;
        wr[g * 2 + ht][s8] = pack8i(*(const float4*)pa, *(const float4*)(pa + 16), LOG2E);
      }
    }
#pragma unroll
  for (int q = 0; q < 16; ++q) {
    int li = tid + q * 512;             // 8192 lines of 16B (n-gate, all 256 rows)
    int wv = li >> 9, s8 = (li >> 6) & 7, l = li & 63;
    int row = 512 + wv * 16 + (l & 15);
    const float* pa = W + row * 256 + s8 * 32 + (l >> 4) * 4;
    *(s16x8*)(Wlds + li * 16) = pack8i(*(const float4*)pa, *(const float4*)(pa + 16),
                                       TWO_LOG2E);
  }
}

// ---------------- Kernel A: input projection -> gi (f16, pre-scaled) ------
__global__ __launch_bounds__(512, 2) void gi_proj_kernel(
    const float* __restrict__ X, const float* __restrict__ w_ih,
    const float* __restrict__ b_ih, const float* __restrict__ b_hh,
    __half* __restrict__ gi) {
  __shared__ __align__(16) char Wlds[131072];
  __shared__ __align__(16) char Ald[2][16384];   // 32x256 bf16, swizzled, dbuf

  const int tid = threadIdx.x;
  const int wid = tid >> 6, lane = tid & 63;
  const int col = lane & 15, kgrp = lane >> 4;

  s16x8 wrA[4][8];
  load_weights_proj(w_ih, wrA, Wlds, tid, wid, col, kgrp);

  float bias[2][3];
#pragma unroll
  for (int ht = 0; ht < 2; ++ht) {
    int gb = wid * 32 + ht * 16 + col;
    bias[ht][0] = (b_ih[gb]       + b_hh[gb])       * LOG2E;   // r (b_hh folded)
    bias[ht][1] = (b_ih[256 + gb] + b_hh[256 + gb]) * LOG2E;   // z (b_hh folded)
    bias[ht][2] = b_ih[512 + gb] * TWO_LOG2E;                  // n (b_hh in scan)
  }

  const int srow = tid >> 4, skb = tid & 15;   // 32 rows x 16 col-blocks
  const unsigned sx = (unsigned)(srow & 7) << 4;
  const unsigned sb0 = (unsigned)(srow * 512 + skb * 32);

  float4 xc0, xc1, xc2, xc3;
  {
    const float* xp = X + (size_t)(blockIdx.x * 32 + srow) * 256 + skb * 16;
    xc0 = *(const float4*)(xp); xc1 = *(const float4*)(xp + 4);
    xc2 = *(const float4*)(xp + 8); xc3 = *(const float4*)(xp + 12);
  }

  int parity = 0;
  for (int c32 = blockIdx.x; c32 < 4096; c32 += 256) {
    char* ab = Ald[parity];
    {
      uint4 u0, u1;
      u0.x = cvt_pk_bf16(xc0.x, xc0.y); u0.y = cvt_pk_bf16(xc0.z, xc0.w);
      u0.z = cvt_pk_bf16(xc1.x, xc1.y); u0.w = cvt_pk_bf16(xc1.z, xc1.w);
      u1.x = cvt_pk_bf16(xc2.x, xc2.y); u1.y = cvt_pk_bf16(xc2.z, xc2.w);
      u1.z = cvt_pk_bf16(xc3.x, xc3.y); u1.w = cvt_pk_bf16(xc3.z, xc3.w);
      *(uint4*)(ab + (sb0 ^ sx)) = u0;
      *(uint4*)(ab + ((sb0 + 16) ^ sx)) = u1;
    }
    int nc = c32 + 256;
    if (nc < 4096) {
      const float* xp = X + (size_t)(nc * 32 + srow) * 256 + skb * 16;
      xc0 = *(const float4*)(xp); xc1 = *(const float4*)(xp + 4);
      xc2 = *(const float4*)(xp + 8); xc3 = *(const float4*)(xp + 12);
    }
    soft_barrier();   // stage visible; X prefetch + gi stores stay in flight

    __half* gb = gi + (size_t)c32 * BLKH + (unsigned)(wid * 64 + lane) * 48;
#pragma unroll
    for (int m = 0; m < 2; ++m) {
      fx4 aR0, aR1, aZ0, aZ1, aN0, aN1;
#pragma unroll
      for (int j = 0; j < 4; ++j) {
        aR0[j] = bias[0][0]; aR1[j] = bias[1][0];
        aZ0[j] = bias[0][1]; aZ1[j] = bias[1][1];
        aN0[j] = bias[0][2]; aN1[j] = bias[1][2];
      }
#pragma unroll
      for (int s8 = 0; s8 < 8; ++s8) {
        unsigned aoff = ((unsigned)((m * 16 + col) * 512 + s8 * 64 + kgrp * 16)) ^
                        ((unsigned)(col & 7) << 4);
        s16x8 af  = *(const s16x8*)(ab + aoff);
        s16x8 wz1 = *(const s16x8*)(Wlds + (wid * 512 + s8 * 64 + lane) * 16);
        s16x8 wn1 = *(const s16x8*)(Wlds + 65536 + (wid * 512 + s8 * 64 + lane) * 16);
        aR0 = MFMA16(af, wrA[0][s8], aR0, 0, 0, 0);
        aR1 = MFMA16(af, wrA[1][s8], aR1, 0, 0, 0);
        aZ0 = MFMA16(af, wrA[2][s8], aZ0, 0, 0, 0);
        aZ1 = MFMA16(af, wz1, aZ1, 0, 0, 0);
        aN0 = MFMA16(af, wrA[3][s8], aN0, 0, 0, 0);
        aN1 = MFMA16(af, wn1, aN1, 0, 0, 0);
      }
      u16x8 oR, oZ, oN;
#pragma unroll
      for (int j = 0; j < 4; ++j) {
        oR[j] = __half_as_ushort(__float2half(aR0[j]));
        oR[4 + j] = __half_as_ushort(__float2half(aR1[j]));
        oZ[j] = __half_as_ushort(__float2half(aZ0[j]));
        oZ[4 + j] = __half_as_ushort(__float2half(aZ1[j]));
        oN[j] = __half_as_ushort(__float2half(aN0[j]));
        oN[4 + j] = __half_as_ushort(__float2half(aN1[j]));
      }
      *(u16x8*)(gb + m * 8) = oR;
      *(u16x8*)(gb + 16 + m * 8) = oZ;
      *(u16x8*)(gb + 32 + m * 8) = oN;
    }
    parity ^= 1;
  }
}

// ---------------- Kernel B: chunked GRU scan (r7 structure) ----------------
__global__ __launch_bounds__(512, 2) void gru_scan_kernel(
    const float* __restrict__ carry, const __half* __restrict__ gi,
    const int* __restrict__ resets, const float* __restrict__ w_hh,
    const float* __restrict__ b_hh, float* __restrict__ out) {
  __shared__ __align__(16) char Wlds[131072];
  __shared__ __align__(16) char Ald[2][8192];   // h bf16 A-tile (sigma K), dbuf
  __shared__ int lastreset[16];

  const int tid = threadIdx.x;
  const int wid = tid >> 6, lane = tid & 63;
  const int col = lane & 15, kgrp = lane >> 4;
  const int bid = blockIdx.x;
  const int bt = bid & 15, c = bid >> 4;
  const int b0 = bt * 16, t0 = c * 32, t1 = t0 + 32;
  const int hid0 = wid * 32 + col;              // wave owns hid0, hid0+16

  s16x8 wr[4][8];
  load_weights_scan(w_hh, wr, Wlds, tid, wid, col, kgrp);
  const float bhhn0 = b_hh[512 + hid0] * TWO_LOG2E;
  const float bhhn1 = b_hh[512 + hid0 + 16] * TWO_LOG2E;

  // ---- exact scan start: min over batch tile of (last reset < t0) ----
  int s, useCarry;
  if (c == 0) {
    s = 0; useCarry = 1;
  } else {
    if (tid < 16) lastreset[tid] = -1;
    for (int base = t0 - 32;; base -= 32) {
      __syncthreads();
      int tt = base + (tid >> 4);
      if (tt >= 0 && tt < t0) {
        if (resets[tt * BATCH + b0 + (tid & 15)] != 0)
          atomicMax(&lastreset[tid & 15], tt);
      }
      __syncthreads();
      int mn = t0, all = 1;
#pragma unroll
      for (int i = 0; i < 16; ++i) {
        int v = lastreset[i];
        all &= (v >= 0) ? 1 : 0;
        mn = min(mn, v < 0 ? t0 : v);
      }
      if (all) { s = mn; useCarry = 0; break; }
      if (base <= 0) { s = 0; useCarry = 1; break; }
    }
  }

  // ---- init state at t=s into Ald[0] (sigma: pairs (hid,hid+16)) ----
  {
    int row = tid >> 5, k0 = (tid & 31) * 8;
    int tile = k0 >> 5, colb = (k0 >> 1) & 15;
    int rst = resets[s * BATCH + b0 + row];
    float4 va = {0.f, 0.f, 0.f, 0.f}, vb = va;
    if (useCarry && !rst) {
      va = *(const float4*)(carry + (size_t)(b0 + row) * HID + tile * 32 + colb);
      vb = *(const float4*)(carry + (size_t)(b0 + row) * HID + tile * 32 + colb + 16);
    }
    uint4 u;
    u.x = cvt_pk_bf16(va.x, vb.x);
    u.y = cvt_pk_bf16(va.y, vb.y);
    u.z = cvt_pk_bf16(va.z, vb.z);
    u.w = cvt_pk_bf16(va.w, vb.w);
    unsigned byteoff = ((unsigned)(row * 512 + k0 * 2)) ^ ((unsigned)(row & 7) << 4);
    *(uint4*)(Ald[0] + byteoff) = u;
  }
  float hprev[2][4];
#pragma unroll
  for (int ht = 0; ht < 2; ++ht)
#pragma unroll
    for (int j = 0; j < 4; ++j) {
      int b = kgrp * 4 + j;
      int rst = resets[s * BATCH + b0 + b];
      float hv = 0.f;
      if (useCarry && !rst) hv = carry[(size_t)(b0 + b) * HID + hid0 + ht * 16];
      hprev[ht][j] = hv;
    }
  __syncthreads();

  // ---- pipelined scan: gi from M=32 blocks, 1-step prefetch ----
  // thread's gi slot in block (t, bt>>1): (wid*64+lane)*48 + (bt&1)*8,
  // gates at stride 16 halves; u16x8 = [ht0 j0..3 | ht1 j0..3].
  const __half* gp = gi + (size_t)(s * 8 + (bt >> 1)) * BLKH +
                     (unsigned)(wid * 64 + lane) * 48 + (unsigned)((bt & 1) * 8);
  const int* rbase = resets + b0 + kgrp * 4;
  float* opc = out + 65536 + ((size_t)s * BATCH + b0 + kgrp * 4) * HID + hid0;

  u16x8 gP0 = *(const u16x8*)(gp);
  u16x8 gP1 = *(const u16x8*)(gp + 16);
  u16x8 gP2 = *(const u16x8*)(gp + 32);
  int4 rnC = *(const int4*)(rbase + (size_t)((s + 1 < T_LEN) ? s + 1 : T_LEN - 1) * BATCH);

  for (int t = s; t < t1; ++t) {
    // (1) VMEM loads for t+1 FIRST (retire never waits on later stores)
    const __half* gq = gp + ((t + 1 < t1) ? TSTRH : 0u);
    u16x8 gN0 = *(const u16x8*)(gq);
    u16x8 gN1 = *(const u16x8*)(gq + 16);
    u16x8 gN2 = *(const u16x8*)(gq + 32);
    int tn = (t + 2 < T_LEN) ? t + 2 : T_LEN - 1;
    int4 rnN = *(const int4*)(rbase + (size_t)tn * BATCH);

    // (2) acc init via C-in: r,z from gi; n from b_hh (all exp2-scaled)
    fx4 a00, a10, a01, a11, a02, a12;
#pragma unroll
    for (int j = 0; j < 4; ++j) {
      a00[j] = __half2float(__ushort_as_half(gP0[j]));
      a10[j] = __half2float(__ushort_as_half(gP0[4 + j]));
      a01[j] = __half2float(__ushort_as_half(gP1[j]));
      a11[j] = __half2float(__ushort_as_half(gP1[4 + j]));
      a02[j] = bhhn0;
      a12[j] = bhhn1;
    }

    // (3) MFMA: 8 af + 16 w2 LDS reads, 48 MFMA
    const char* ab = Ald[(t - s) & 1];
#pragma unroll
    for (int s8 = 0; s8 < 8; ++s8) {
      unsigned aoff = ((unsigned)(col * 512 + (s8 * 32 + kgrp * 8) * 2)) ^
                      ((unsigned)(col & 7) << 4);
      s16x8 af  = *(const s16x8*)(ab + aoff);
      s16x8 w2a = *(const s16x8*)(Wlds + (((wid * 2 + 0) * 8 + s8) * 64 + lane) * 16);
      s16x8 w2b = *(const s16x8*)(Wlds + (((wid * 2 + 1) * 8 + s8) * 64 + lane) * 16);
      a00 = MFMA16(af, wr[0][s8], a00, 0, 0, 0);
      a10 = MFMA16(af, wr[1][s8], a10, 0, 0, 0);
      a01 = MFMA16(af, wr[2][s8], a01, 0, 0, 0);
      a11 = MFMA16(af, wr[3][s8], a11, 0, 0, 0);
      a02 = MFMA16(af, w2a, a02, 0, 0, 0);
      a12 = MFMA16(af, w2b, a12, 0, 0, 0);
    }

    // (4) gates + out stores + h LDS write (paired b32, sigma layout)
    char* aw = (char*)Ald[((t - s) & 1) ^ 1];
    const bool wr_out = (t >= t0);
    const bool lastT = (t + 1 >= T_LEN);
#pragma unroll
    for (int j = 0; j < 4; ++j) {
      int b = kgrp * 4 + j;
      int rj = (j == 0) ? rnC.x : (j == 1) ? rnC.y : (j == 2) ? rnC.z : rnC.w;
      if (lastT) rj = 0;

      float r0 = __builtin_amdgcn_rcpf(1.f + __builtin_amdgcn_exp2f(-a00[j]));
      float z0 = __builtin_amdgcn_rcpf(1.f + __builtin_amdgcn_exp2f(-a01[j]));
      float pn0 = __half2float(__ushort_as_half(gP2[j])) + r0 * a02[j];
      float n0 = 1.f - 2.f * __builtin_amdgcn_rcpf(1.f + __builtin_amdgcn_exp2f(pn0));
      float h0 = n0 + z0 * (hprev[0][j] - n0);

      float r1 = __builtin_amdgcn_rcpf(1.f + __builtin_amdgcn_exp2f(-a10[j]));
      float z1 = __builtin_amdgcn_rcpf(1.f + __builtin_amdgcn_exp2f(-a11[j]));
      float pn1 = __half2float(__ushort_as_half(gP2[4 + j])) + r1 * a12[j];
      float n1 = 1.f - 2.f * __builtin_amdgcn_rcpf(1.f + __builtin_amdgcn_exp2f(pn1));
      float h1 = n1 + z1 * (hprev[1][j] - n1);

      if (wr_out) {
        __builtin_nontemporal_store(h0, opc + j * HID);
        __builtin_nontemporal_store(h1, opc + j * HID + 16);
      }

      float hk0 = rj ? 0.f : h0;      // pre-apply reset[t+1]
      float hk1 = rj ? 0.f : h1;
      hprev[0][j] = hk0; hprev[1][j] = hk1;

      unsigned hw = cvt_pk_bf16(hk0, hk1);
      unsigned hoff = ((unsigned)(b * 512 + wid * 64 + col * 4)) ^
                      ((unsigned)(b & 7) << 4);
      *(unsigned*)(aw + hoff) = hw;
    }

    gP0 = gN0; gP1 = gN1; gP2 = gN2; rnC = rnN;
    gp = gq;
    opc += 65536;
    soft_barrier();   // lgkm drain only; gi prefetch + out stores in flight
  }

  if (c == 15) {       // h_final = h after t=511 (reset guarded off)
#pragma unroll
    for (int ht = 0; ht < 2; ++ht)
#pragma unroll
      for (int j = 0; j < 4; ++j)
        out[(size_t)(b0 + kgrp * 4 + j) * HID + hid0 + ht * 16] = hprev[ht][j];
  }
}

extern "C" void kernel_launch(void* const* d_in, const int* in_sizes, int n_in,
                              void* d_out, int out_size, void* d_ws, size_t ws_size,
                              hipStream_t stream) {
  const float* carry = (const float*)d_in[0];
  const float* X     = (const float*)d_in[1];
  const int*   rsts  = (const int*)d_in[2];
  const float* w_ih  = (const float*)d_in[3];
  const float* w_hh  = (const float*)d_in[4];
  const float* b_ih  = (const float*)d_in[5];
  const float* b_hh  = (const float*)d_in[6];
  float* out = (float*)d_out;

  const size_t gi_bytes = (size_t)T_LEN * BATCH * 3 * HID * sizeof(__half);  // 192 MiB
  if (ws_size < gi_bytes) return;
  __half* gi = (__half*)d_ws;

  gi_proj_kernel<<<256, 512, 0, stream>>>(X, w_ih, b_ih, b_hh, gi);
  gru_scan_kernel<<<256, 512, 0, stream>>>(carry, gi, rsts, w_hh, b_hh, out);
}

// Round 12
// 255.754 us; speedup vs baseline: 1.4613x; 1.0413x over previous
//
#include <hip/hip_runtime.h>
#include <hip/hip_bf16.h>
#include <hip/hip_fp16.h>

// ScannedRNN (GRU with resets), T=512 B=256 H=INP=256, MI355X gfx950.
//
// Round 12: r11 with the gi address map fixed so each 16-batch tile's slice
// is CONTIGUOUS (WG-private 24 KiB/step) again -- r11 interleaved the two
// halves of each 32-batch block at 16B granularity, so two WGs on different
// XCDs split every cache line (FETCH 135->269 MB, scan 151->182 us).
//  - gi layout: sub-block (t*16+bt16)*12288 halves, inside: [g][wid][lane][ht*4+j]
//    (gate stride 4096) -- exactly r7's layout; proj (M=32) writes m-phase m
//    to sub-block 2*c32+m (6 x 16B coalesced stores, same count as r11).
//  - scan: r7 structure verbatim + exp2-folded gates: 16 chunks x 32 steps,
//    weights {r0,r1,z0,z1} in 128 AGPRs + n-gate both tiles in 128 KiB LDS,
//    sigma K-pairing h-writes via cvt_pk, C-in acc init, 1-step gi prefetch,
//    one lgkm-only barrier/step, nontemporal out stores.

#define T_LEN 512
#define BATCH 256
#define HID   256

#define LOG2E     1.4426950408889634f
#define TWO_LOG2E 2.8853900817779268f

typedef __attribute__((ext_vector_type(8))) short s16x8;          // 8 bf16
typedef __attribute__((ext_vector_type(8))) unsigned short u16x8; // 8 f16
typedef __attribute__((ext_vector_type(4))) float fx4;            // 4 f32 acc

#define MFMA16 __builtin_amdgcn_mfma_f32_16x16x32_bf16
#define SUBBLK 12288u               /* halves per (t,bt16) gi sub-block (24 KiB) */
#define GSTR   4096u                /* gate stride inside sub-block */
#define TSTRH  196608u              /* 16 sub-blocks per t */

__device__ __forceinline__ unsigned short f2bf(float f) {
  union { float f; unsigned u; } v; v.f = f;
  unsigned r = v.u + 0x7fffu + ((v.u >> 16) & 1u);   // RNE
  return (unsigned short)(r >> 16);
}

__device__ __forceinline__ unsigned cvt_pk_bf16(float lo, float hi) {
  unsigned r;
  asm("v_cvt_pk_bf16_f32 %0, %1, %2" : "=v"(r) : "v"(lo), "v"(hi));
  return r;
}

__device__ __forceinline__ s16x8 pack8(float4 a, float4 b, float s) {  // natural K
  s16x8 f;
  f[0] = (short)f2bf(a.x * s); f[1] = (short)f2bf(a.y * s);
  f[2] = (short)f2bf(a.z * s); f[3] = (short)f2bf(a.w * s);
  f[4] = (short)f2bf(b.x * s); f[5] = (short)f2bf(b.y * s);
  f[6] = (short)f2bf(b.z * s); f[7] = (short)f2bf(b.w * s);
  return f;
}

__device__ __forceinline__ s16x8 pack8i(float4 a, float4 b, float s) { // sigma K
  s16x8 f;
  f[0] = (short)f2bf(a.x * s); f[1] = (short)f2bf(b.x * s);
  f[2] = (short)f2bf(a.y * s); f[3] = (short)f2bf(b.y * s);
  f[4] = (short)f2bf(a.z * s); f[5] = (short)f2bf(b.z * s);
  f[6] = (short)f2bf(a.w * s); f[7] = (short)f2bf(b.w * s);
  return f;
}

__device__ __forceinline__ void soft_barrier() {
  asm volatile("s_waitcnt lgkmcnt(0)" ::: "memory");
  __builtin_amdgcn_s_barrier();
  __builtin_amdgcn_sched_barrier(0);
  asm volatile("" ::: "memory");
}

// ---- proj weights: wrA {r/ht0,r/ht1,z/ht0,n/ht0} AGPR; LDS {z/ht1,n/ht1} ----
__device__ __forceinline__ void load_weights_proj(const float* __restrict__ W,
                                                  s16x8 (&wrA)[4][8], char* Wlds,
                                                  int tid, int wid, int col, int kgrp) {
  const int rowbase[4] = {0, 16, 256, 512};
  const float scl[4] = {LOG2E, LOG2E, LOG2E, TWO_LOG2E};
#pragma unroll
  for (int k = 0; k < 4; ++k) {
    int row = rowbase[k] + wid * 32 + col;
#pragma unroll
    for (int s8 = 0; s8 < 8; ++s8) {
      const float* pa = W + row * 256 + s8 * 32 + kgrp * 8;
      wrA[k][s8] = pack8(*(const float4*)pa, *(const float4*)(pa + 4), scl[k]);
    }
  }
#pragma unroll
  for (int q = 0; q < 16; ++q) {
    int li = tid + q * 512;             // 8192 lines of 16 B
    int set = li >> 12, wv = (li >> 9) & 7, s8 = (li >> 6) & 7, l = li & 63;
    int row = (set ? 512 : 256) + wv * 32 + 16 + (l & 15);
    float s = set ? TWO_LOG2E : LOG2E;
    const float* pa = W + row * 256 + s8 * 32 + (l >> 4) * 8;
    *(s16x8*)(Wlds + li * 16) = pack8(*(const float4*)pa, *(const float4*)(pa + 4), s);
  }
}

// ---- scan weights: wr {r/ht0,r/ht1,z/ht0,z/ht1} AGPR; LDS n both tiles ----
__device__ __forceinline__ void load_weights_scan(const float* __restrict__ W,
                                                  s16x8 (&wr)[4][8], char* Wlds,
                                                  int tid, int wid, int col, int kgrp) {
#pragma unroll
  for (int g = 0; g < 2; ++g)
#pragma unroll
    for (int ht = 0; ht < 2; ++ht) {
      int row = g * 256 + (wid * 2 + ht) * 16 + col;
#pragma unroll
      for (int s8 = 0; s8 < 8; ++s8) {
        const float* pa = W + row * 256 + s8 * 32 + kgrp * 4;
        wr[g * 2 + ht][s8] = pack8i(*(const float4*)pa, *(const float4*)(pa + 16), LOG2E);
      }
    }
#pragma unroll
  for (int q = 0; q < 16; ++q) {
    int li = tid + q * 512;             // 8192 lines of 16B (n-gate, all 256 rows)
    int wv = li >> 9, s8 = (li >> 6) & 7, l = li & 63;
    int row = 512 + wv * 16 + (l & 15);
    const float* pa = W + row * 256 + s8 * 32 + (l >> 4) * 4;
    *(s16x8*)(Wlds + li * 16) = pack8i(*(const float4*)pa, *(const float4*)(pa + 16),
                                       TWO_LOG2E);
  }
}

// ---------------- Kernel A: input projection -> gi (f16, pre-scaled) ------
__global__ __launch_bounds__(512, 2) void gi_proj_kernel(
    const float* __restrict__ X, const float* __restrict__ w_ih,
    const float* __restrict__ b_ih, const float* __restrict__ b_hh,
    __half* __restrict__ gi) {
  __shared__ __align__(16) char Wlds[131072];
  __shared__ __align__(16) char Ald[2][16384];   // 32x256 bf16, swizzled, dbuf

  const int tid = threadIdx.x;
  const int wid = tid >> 6, lane = tid & 63;
  const int col = lane & 15, kgrp = lane >> 4;

  s16x8 wrA[4][8];
  load_weights_proj(w_ih, wrA, Wlds, tid, wid, col, kgrp);

  float bias[2][3];
#pragma unroll
  for (int ht = 0; ht < 2; ++ht) {
    int gb = wid * 32 + ht * 16 + col;
    bias[ht][0] = (b_ih[gb]       + b_hh[gb])       * LOG2E;   // r (b_hh folded)
    bias[ht][1] = (b_ih[256 + gb] + b_hh[256 + gb]) * LOG2E;   // z (b_hh folded)
    bias[ht][2] = b_ih[512 + gb] * TWO_LOG2E;                  // n (b_hh in scan)
  }

  const int srow = tid >> 4, skb = tid & 15;   // 32 rows x 16 col-blocks
  const unsigned sx = (unsigned)(srow & 7) << 4;
  const unsigned sb0 = (unsigned)(srow * 512 + skb * 32);

  float4 xc0, xc1, xc2, xc3;
  {
    const float* xp = X + (size_t)(blockIdx.x * 32 + srow) * 256 + skb * 16;
    xc0 = *(const float4*)(xp); xc1 = *(const float4*)(xp + 4);
    xc2 = *(const float4*)(xp + 8); xc3 = *(const float4*)(xp + 12);
  }

  int parity = 0;
  for (int c32 = blockIdx.x; c32 < 4096; c32 += 256) {
    char* ab = Ald[parity];
    {
      uint4 u0, u1;
      u0.x = cvt_pk_bf16(xc0.x, xc0.y); u0.y = cvt_pk_bf16(xc0.z, xc0.w);
      u0.z = cvt_pk_bf16(xc1.x, xc1.y); u0.w = cvt_pk_bf16(xc1.z, xc1.w);
      u1.x = cvt_pk_bf16(xc2.x, xc2.y); u1.y = cvt_pk_bf16(xc2.z, xc2.w);
      u1.z = cvt_pk_bf16(xc3.x, xc3.y); u1.w = cvt_pk_bf16(xc3.z, xc3.w);
      *(uint4*)(ab + (sb0 ^ sx)) = u0;
      *(uint4*)(ab + ((sb0 + 16) ^ sx)) = u1;
    }
    int nc = c32 + 256;
    if (nc < 4096) {
      const float* xp = X + (size_t)(nc * 32 + srow) * 256 + skb * 16;
      xc0 = *(const float4*)(xp); xc1 = *(const float4*)(xp + 4);
      xc2 = *(const float4*)(xp + 8); xc3 = *(const float4*)(xp + 12);
    }
    soft_barrier();   // stage visible; X prefetch + gi stores stay in flight

    // sub-blocks: m-phase m -> (2*c32+m)*SUBBLK, thread slot (wid*64+lane)*8
    __half* gb0 = gi + (size_t)(2 * c32) * SUBBLK + (unsigned)(wid * 64 + lane) * 8;
#pragma unroll
    for (int m = 0; m < 2; ++m) {
      fx4 aR0, aR1, aZ0, aZ1, aN0, aN1;
#pragma unroll
      for (int j = 0; j < 4; ++j) {
        aR0[j] = bias[0][0]; aR1[j] = bias[1][0];
        aZ0[j] = bias[0][1]; aZ1[j] = bias[1][1];
        aN0[j] = bias[0][2]; aN1[j] = bias[1][2];
      }
#pragma unroll
      for (int s8 = 0; s8 < 8; ++s8) {
        unsigned aoff = ((unsigned)((m * 16 + col) * 512 + s8 * 64 + kgrp * 16)) ^
                        ((unsigned)(col & 7) << 4);
        s16x8 af  = *(const s16x8*)(ab + aoff);
        s16x8 wz1 = *(const s16x8*)(Wlds + (wid * 512 + s8 * 64 + lane) * 16);
        s16x8 wn1 = *(const s16x8*)(Wlds + 65536 + (wid * 512 + s8 * 64 + lane) * 16);
        aR0 = MFMA16(af, wrA[0][s8], aR0, 0, 0, 0);
        aR1 = MFMA16(af, wrA[1][s8], aR1, 0, 0, 0);
        aZ0 = MFMA16(af, wrA[2][s8], aZ0, 0, 0, 0);
        aZ1 = MFMA16(af, wz1, aZ1, 0, 0, 0);
        aN0 = MFMA16(af, wrA[3][s8], aN0, 0, 0, 0);
        aN1 = MFMA16(af, wn1, aN1, 0, 0, 0);
      }
      u16x8 oR, oZ, oN;
#pragma unroll
      for (int j = 0; j < 4; ++j) {
        oR[j] = __half_as_ushort(__float2half(aR0[j]));
        oR[4 + j] = __half_as_ushort(__float2half(aR1[j]));
        oZ[j] = __half_as_ushort(__float2half(aZ0[j]));
        oZ[4 + j] = __half_as_ushort(__float2half(aZ1[j]));
        oN[j] = __half_as_ushort(__float2half(aN0[j]));
        oN[4 + j] = __half_as_ushort(__float2half(aN1[j]));
      }
      __half* gm = gb0 + m * SUBBLK;
      *(u16x8*)(gm) = oR;
      *(u16x8*)(gm + GSTR) = oZ;
      *(u16x8*)(gm + 2 * GSTR) = oN;
    }
    parity ^= 1;
  }
}

// ---------------- Kernel B: chunked GRU scan (r7 structure) ----------------
__global__ __launch_bounds__(512, 2) void gru_scan_kernel(
    const float* __restrict__ carry, const __half* __restrict__ gi,
    const int* __restrict__ resets, const float* __restrict__ w_hh,
    const float* __restrict__ b_hh, float* __restrict__ out) {
  __shared__ __align__(16) char Wlds[131072];
  __shared__ __align__(16) char Ald[2][8192];   // h bf16 A-tile (sigma K), dbuf
  __shared__ int lastreset[16];

  const int tid = threadIdx.x;
  const int wid = tid >> 6, lane = tid & 63;
  const int col = lane & 15, kgrp = lane >> 4;
  const int bid = blockIdx.x;
  const int bt = bid & 15, c = bid >> 4;
  const int b0 = bt * 16, t0 = c * 32, t1 = t0 + 32;
  const int hid0 = wid * 32 + col;              // wave owns hid0, hid0+16

  s16x8 wr[4][8];
  load_weights_scan(w_hh, wr, Wlds, tid, wid, col, kgrp);
  const float bhhn0 = b_hh[512 + hid0] * TWO_LOG2E;
  const float bhhn1 = b_hh[512 + hid0 + 16] * TWO_LOG2E;

  // ---- exact scan start: min over batch tile of (last reset < t0) ----
  int s, useCarry;
  if (c == 0) {
    s = 0; useCarry = 1;
  } else {
    if (tid < 16) lastreset[tid] = -1;
    for (int base = t0 - 32;; base -= 32) {
      __syncthreads();
      int tt = base + (tid >> 4);
      if (tt >= 0 && tt < t0) {
        if (resets[tt * BATCH + b0 + (tid & 15)] != 0)
          atomicMax(&lastreset[tid & 15], tt);
      }
      __syncthreads();
      int mn = t0, all = 1;
#pragma unroll
      for (int i = 0; i < 16; ++i) {
        int v = lastreset[i];
        all &= (v >= 0) ? 1 : 0;
        mn = min(mn, v < 0 ? t0 : v);
      }
      if (all) { s = mn; useCarry = 0; break; }
      if (base <= 0) { s = 0; useCarry = 1; break; }
    }
  }

  // ---- init state at t=s into Ald[0] (sigma: pairs (hid,hid+16)) ----
  {
    int row = tid >> 5, k0 = (tid & 31) * 8;
    int tile = k0 >> 5, colb = (k0 >> 1) & 15;
    int rst = resets[s * BATCH + b0 + row];
    float4 va = {0.f, 0.f, 0.f, 0.f}, vb = va;
    if (useCarry && !rst) {
      va = *(const float4*)(carry + (size_t)(b0 + row) * HID + tile * 32 + colb);
      vb = *(const float4*)(carry + (size_t)(b0 + row) * HID + tile * 32 + colb + 16);
    }
    uint4 u;
    u.x = cvt_pk_bf16(va.x, vb.x);
    u.y = cvt_pk_bf16(va.y, vb.y);
    u.z = cvt_pk_bf16(va.z, vb.z);
    u.w = cvt_pk_bf16(va.w, vb.w);
    unsigned byteoff = ((unsigned)(row * 512 + k0 * 2)) ^ ((unsigned)(row & 7) << 4);
    *(uint4*)(Ald[0] + byteoff) = u;
  }
  float hprev[2][4];
#pragma unroll
  for (int ht = 0; ht < 2; ++ht)
#pragma unroll
    for (int j = 0; j < 4; ++j) {
      int b = kgrp * 4 + j;
      int rst = resets[s * BATCH + b0 + b];
      float hv = 0.f;
      if (useCarry && !rst) hv = carry[(size_t)(b0 + b) * HID + hid0 + ht * 16];
      hprev[ht][j] = hv;
    }
  __syncthreads();

  // ---- pipelined scan: WG-private gi sub-blocks, 1-step prefetch ----
  const __half* gp = gi + (size_t)(s * 16 + bt) * SUBBLK + (unsigned)(wid * 64 + lane) * 8;
  const int* rbase = resets + b0 + kgrp * 4;
  float* opc = out + 65536 + ((size_t)s * BATCH + b0 + kgrp * 4) * HID + hid0;

  u16x8 gP0 = *(const u16x8*)(gp);
  u16x8 gP1 = *(const u16x8*)(gp + GSTR);
  u16x8 gP2 = *(const u16x8*)(gp + 2 * GSTR);
  int4 rnC = *(const int4*)(rbase + (size_t)((s + 1 < T_LEN) ? s + 1 : T_LEN - 1) * BATCH);

  for (int t = s; t < t1; ++t) {
    // (1) VMEM loads for t+1 FIRST (retire never waits on later stores)
    const __half* gq = gp + ((t + 1 < t1) ? TSTRH : 0u);
    u16x8 gN0 = *(const u16x8*)(gq);
    u16x8 gN1 = *(const u16x8*)(gq + GSTR);
    u16x8 gN2 = *(const u16x8*)(gq + 2 * GSTR);
    int tn = (t + 2 < T_LEN) ? t + 2 : T_LEN - 1;
    int4 rnN = *(const int4*)(rbase + (size_t)tn * BATCH);

    // (2) acc init via C-in: r,z from gi; n from b_hh (all exp2-scaled)
    fx4 a00, a10, a01, a11, a02, a12;
#pragma unroll
    for (int j = 0; j < 4; ++j) {
      a00[j] = __half2float(__ushort_as_half(gP0[j]));
      a10[j] = __half2float(__ushort_as_half(gP0[4 + j]));
      a01[j] = __half2float(__ushort_as_half(gP1[j]));
      a11[j] = __half2float(__ushort_as_half(gP1[4 + j]));
      a02[j] = bhhn0;
      a12[j] = bhhn1;
    }

    // (3) MFMA: 8 af + 16 w2 LDS reads, 48 MFMA
    const char* ab = Ald[(t - s) & 1];
#pragma unroll
    for (int s8 = 0; s8 < 8; ++s8) {
      unsigned aoff = ((unsigned)(col * 512 + (s8 * 32 + kgrp * 8) * 2)) ^
                      ((unsigned)(col & 7) << 4);
      s16x8 af  = *(const s16x8*)(ab + aoff);
      s16x8 w2a = *(const s16x8*)(Wlds + (((wid * 2 + 0) * 8 + s8) * 64 + lane) * 16);
      s16x8 w2b = *(const s16x8*)(Wlds + (((wid * 2 + 1) * 8 + s8) * 64 + lane) * 16);
      a00 = MFMA16(af, wr[0][s8], a00, 0, 0, 0);
      a10 = MFMA16(af, wr[1][s8], a10, 0, 0, 0);
      a01 = MFMA16(af, wr[2][s8], a01, 0, 0, 0);
      a11 = MFMA16(af, wr[3][s8], a11, 0, 0, 0);
      a02 = MFMA16(af, w2a, a02, 0, 0, 0);
      a12 = MFMA16(af, w2b, a12, 0, 0, 0);
    }

    // (4) gates + out stores + h LDS write (paired b32, sigma layout)
    char* aw = (char*)Ald[((t - s) & 1) ^ 1];
    const bool wr_out = (t >= t0);
    const bool lastT = (t + 1 >= T_LEN);
#pragma unroll
    for (int j = 0; j < 4; ++j) {
      int b = kgrp * 4 + j;
      int rj = (j == 0) ? rnC.x : (j == 1) ? rnC.y : (j == 2) ? rnC.z : rnC.w;
      if (lastT) rj = 0;

      float r0 = __builtin_amdgcn_rcpf(1.f + __builtin_amdgcn_exp2f(-a00[j]));
      float z0 = __builtin_amdgcn_rcpf(1.f + __builtin_amdgcn_exp2f(-a01[j]));
      float pn0 = __half2float(__ushort_as_half(gP2[j])) + r0 * a02[j];
      float n0 = 1.f - 2.f * __builtin_amdgcn_rcpf(1.f + __builtin_amdgcn_exp2f(pn0));
      float h0 = n0 + z0 * (hprev[0][j] - n0);

      float r1 = __builtin_amdgcn_rcpf(1.f + __builtin_amdgcn_exp2f(-a10[j]));
      float z1 = __builtin_amdgcn_rcpf(1.f + __builtin_amdgcn_exp2f(-a11[j]));
      float pn1 = __half2float(__ushort_as_half(gP2[4 + j])) + r1 * a12[j];
      float n1 = 1.f - 2.f * __builtin_amdgcn_rcpf(1.f + __builtin_amdgcn_exp2f(pn1));
      float h1 = n1 + z1 * (hprev[1][j] - n1);

      if (wr_out) {
        __builtin_nontemporal_store(h0, opc + j * HID);
        __builtin_nontemporal_store(h1, opc + j * HID + 16);
      }

      float hk0 = rj ? 0.f : h0;      // pre-apply reset[t+1]
      float hk1 = rj ? 0.f : h1;
      hprev[0][j] = hk0; hprev[1][j] = hk1;

      unsigned hw = cvt_pk_bf16(hk0, hk1);
      unsigned hoff = ((unsigned)(b * 512 + wid * 64 + col * 4)) ^
                      ((unsigned)(b & 7) << 4);
      *(unsigned*)(aw + hoff) = hw;
    }

    gP0 = gN0; gP1 = gN1; gP2 = gN2; rnC = rnN;
    gp = gq;
    opc += 65536;
    soft_barrier();   // lgkm drain only; gi prefetch + out stores in flight
  }

  if (c == 15) {       // h_final = h after t=511 (reset guarded off)
#pragma unroll
    for (int ht = 0; ht < 2; ++ht)
#pragma unroll
      for (int j = 0; j < 4; ++j)
        out[(size_t)(b0 + kgrp * 4 + j) * HID + hid0 + ht * 16] = hprev[ht][j];
  }
}

extern "C" void kernel_launch(void* const* d_in, const int* in_sizes, int n_in,
                              void* d_out, int out_size, void* d_ws, size_t ws_size,
                              hipStream_t stream) {
  const float* carry = (const float*)d_in[0];
  const float* X     = (const float*)d_in[1];
  const int*   rsts  = (const int*)d_in[2];
  const float* w_ih  = (const float*)d_in[3];
  const float* w_hh  = (const float*)d_in[4];
  const float* b_ih  = (const float*)d_in[5];
  const float* b_hh  = (const float*)d_in[6];
  float* out = (float*)d_out;

  const size_t gi_bytes = (size_t)T_LEN * BATCH * 3 * HID * sizeof(__half);  // 192 MiB
  if (ws_size < gi_bytes) return;
  __half* gi = (__half*)d_ws;

  gi_proj_kernel<<<256, 512, 0, stream>>>(X, w_ih, b_ih, b_hh, gi);
  gru_scan_kernel<<<256, 512, 0, stream>>>(carry, gi, rsts, w_hh, b_hh, out);
}